// Round 5
// baseline (173.691 us; speedup 1.0000x reference)
//
#include <hip/hip_runtime.h>
#include <hip/hip_fp16.h>
#include <math.h>

#define N_PTS 50000
#define C_DIM 64
#define K_RAD 32
#define K_KNN 10
#define E_RAD (N_PTS * K_RAD)

// ROCm hip_fp16.h has no __hmax2; emit packed fp16 max directly.
__device__ inline __half2 hmax2(__half2 a, __half2 b) {
    __half2 d;
    asm("v_pk_max_f16 %0, %1, %2" : "=v"(d) : "v"(a), "v"(b));
    return d;
}

__device__ inline __half2 shfl_xor_h2(__half2 v, int mask) {
    int i = *(int*)&v;
    int r = __shfl_xor(i, mask);
    return *(__half2*)&r;
}

// ---------------- K2: fused edge-weight + layer 1 (one-hot input) --------
// One wave per node. Lanes 0..31 compute the rigid weight for edge
// (node*32 + lane), pack (src<<16)|half(w) for later kernels, and scatter
// w into a per-wave 64-entry LDS array with atomicMax (int-bits max ==
// float max for w > 0). Each lane then reads its channel.
__global__ void ew_layer1_kernel(const float* __restrict__ x0,
                                 const float* __restrict__ pos0,
                                 const float* __restrict__ R0,
                                 const float* __restrict__ t0,
                                 const int* __restrict__ src,
                                 const int* __restrict__ assign,
                                 unsigned int* __restrict__ packed,
                                 __half* __restrict__ m1,
                                 float* __restrict__ sum1) {
    __shared__ int lm[4][C_DIM];
    int wave = (blockIdx.x * blockDim.x + threadIdx.x) >> 6;
    int lane = threadIdx.x & 63;
    int wslot = threadIdx.x >> 6;
    if (wave >= N_PTS) return;
    lm[wslot][lane] = 0;
    int base = wave * K_RAD;
    float w = 0.0f;
    int a = 0;
    if (lane < 32) {
        int s = src[base + lane];
        a = assign[s];
        const float* R = R0 + wave * 9;
        float px = pos0[s * 3 + 0], py = pos0[s * 3 + 1], pz = pos0[s * 3 + 2];
        float r0 = R[0] * px + R[1] * py + R[2] * pz + t0[wave * 3 + 0] - x0[s * 3 + 0];
        float r1 = R[3] * px + R[4] * py + R[5] * pz + t0[wave * 3 + 1] - x0[s * 3 + 1];
        float r2 = R[6] * px + R[7] * py + R[8] * pz + t0[wave * 3 + 2] - x0[s * 3 + 2];
        float dsq = r0 * r0 + r1 * r1 + r2 * r2;
        w = 1.0f / (1.0f + __expf(dsq - 0.01f));
        unsigned int wb = (unsigned int)__half_as_ushort(__float2half_rn(w));
        packed[base + lane] = ((unsigned int)s << 16) | wb;
    }
    __syncthreads();
    if (lane < 32) atomicMax(&lm[wslot][a], __float_as_int(w));
    __syncthreads();
    float m = __int_as_float(lm[wslot][lane]);
    if (lane < 32) {
        float lo = __int_as_float(lm[wslot][2 * lane]);
        float hi = __int_as_float(lm[wslot][2 * lane + 1]);
        *(__half2*)(m1 + wave * C_DIM + 2 * lane) = __floats2half2_rn(lo, hi);
    }
    float ssum = m;
#pragma unroll
    for (int off = 32; off > 0; off >>= 1) ssum += __shfl_down(ssum, off);
    if (lane == 0) sum1[wave] = ssum;
}

// ---------------- K3: wide-gather fp16 layer ----------------
// One wave per node. lane = (eslot in [0,8), cpos in [0,8)).
// Iteration p: edge e = p*8+eslot; one bpermute of packed (src,w), one 16B
// global_load_dwordx4 covering channels [cpos*8, cpos*8+8). Only 4 iters.
// Max over eslot via 3 xor-butterflies; coalesced 16B store from lanes 0..7.
__global__ void layer_pk_kernel(const unsigned int* __restrict__ packed,
                                const __half* __restrict__ xin,
                                __half* __restrict__ xout,
                                float* __restrict__ sum_out) {
    int wave = (blockIdx.x * blockDim.x + threadIdx.x) >> 6;
    int lane = threadIdx.x & 63;
    if (wave >= N_PTS) return;
    int eslot = lane >> 3;
    int cpos = lane & 7;
    unsigned int pk = packed[wave * K_RAD + (lane & 31)];
    __half2 a0 = __float2half2_rn(0.0f), a1 = a0, a2 = a0, a3 = a0;
#pragma unroll
    for (int p = 0; p < 4; ++p) {
        unsigned int pe = (unsigned int)__shfl((int)pk, p * 8 + eslot);
        float4 f = *(const float4*)(xin + (pe >> 16) * C_DIM + cpos * 8);
        __half2* h = (__half2*)&f;
        __half2 w2 = __half2half2(__ushort_as_half((unsigned short)(pe & 0xffffu)));
        a0 = hmax2(a0, __hmul2(w2, h[0]));
        a1 = hmax2(a1, __hmul2(w2, h[1]));
        a2 = hmax2(a2, __hmul2(w2, h[2]));
        a3 = hmax2(a3, __hmul2(w2, h[3]));
    }
#pragma unroll
    for (int off = 8; off < 64; off <<= 1) {
        a0 = hmax2(a0, shfl_xor_h2(a0, off));
        a1 = hmax2(a1, shfl_xor_h2(a1, off));
        a2 = hmax2(a2, shfl_xor_h2(a2, off));
        a3 = hmax2(a3, shfl_xor_h2(a3, off));
    }
    if (eslot == 0) {
        float4 o;
        __half2* oh = (__half2*)&o;
        oh[0] = a0; oh[1] = a1; oh[2] = a2; oh[3] = a3;
        ((float4*)(xout + wave * C_DIM))[cpos] = o;
    }
    float2 v0 = __half22float2(a0), v1 = __half22float2(a1);
    float2 v2 = __half22float2(a2), v3 = __half22float2(a3);
    float s = v0.x + v0.y + v1.x + v1.y + v2.x + v2.y + v3.x + v3.y;
#pragma unroll
    for (int off = 1; off < 8; off <<= 1) s += __shfl_xor(s, off);
    if (lane == 0) sum_out[wave] = s;
}

// ---------------- K4: wide-gather layer 3 + fused confidence ----------------
// m3 == m4 == m5  =>  conf = sigmoid(sum1 + sum2 + 3*sum3 - 17)
__global__ void layer3_conf_pk_kernel(const unsigned int* __restrict__ packed,
                                      const __half* __restrict__ xin,
                                      const float* __restrict__ sum1,
                                      const float* __restrict__ sum2,
                                      float* __restrict__ conf) {
    int wave = (blockIdx.x * blockDim.x + threadIdx.x) >> 6;
    int lane = threadIdx.x & 63;
    if (wave >= N_PTS) return;
    int eslot = lane >> 3;
    int cpos = lane & 7;
    unsigned int pk = packed[wave * K_RAD + (lane & 31)];
    __half2 a0 = __float2half2_rn(0.0f), a1 = a0, a2 = a0, a3 = a0;
#pragma unroll
    for (int p = 0; p < 4; ++p) {
        unsigned int pe = (unsigned int)__shfl((int)pk, p * 8 + eslot);
        float4 f = *(const float4*)(xin + (pe >> 16) * C_DIM + cpos * 8);
        __half2* h = (__half2*)&f;
        __half2 w2 = __half2half2(__ushort_as_half((unsigned short)(pe & 0xffffu)));
        a0 = hmax2(a0, __hmul2(w2, h[0]));
        a1 = hmax2(a1, __hmul2(w2, h[1]));
        a2 = hmax2(a2, __hmul2(w2, h[2]));
        a3 = hmax2(a3, __hmul2(w2, h[3]));
    }
#pragma unroll
    for (int off = 8; off < 64; off <<= 1) {
        a0 = hmax2(a0, shfl_xor_h2(a0, off));
        a1 = hmax2(a1, shfl_xor_h2(a1, off));
        a2 = hmax2(a2, shfl_xor_h2(a2, off));
        a3 = hmax2(a3, shfl_xor_h2(a3, off));
    }
    float2 v0 = __half22float2(a0), v1 = __half22float2(a1);
    float2 v2 = __half22float2(a2), v3 = __half22float2(a3);
    float s = v0.x + v0.y + v1.x + v1.y + v2.x + v2.y + v3.x + v3.y;
#pragma unroll
    for (int off = 1; off < 8; off <<= 1) s += __shfl_xor(s, off);
    if (lane == 0) {
        float tot = sum1[wave] + sum2[wave] + 3.0f * s - 17.0f;
        conf[wave] = 1.0f / (1.0f + __expf(-tot));
    }
}

// ---------------- K5: weighted average over knn + rigid transform --------
__global__ void wavg_kernel(const int* __restrict__ knn_src,
                            const float* __restrict__ conf,
                            const float* __restrict__ R0,
                            const float* __restrict__ t0,
                            const float* __restrict__ pos0,
                            float* __restrict__ out) {
    int t = blockIdx.x * blockDim.x + threadIdx.x;
    if (t >= N_PTS) return;
    float nR[9] = {0, 0, 0, 0, 0, 0, 0, 0, 0};
    float nt0 = 0.0f, nt1 = 0.0f, nt2 = 0.0f;
    float den = 1e-8f;
    for (int j = 0; j < K_KNN; ++j) {
        int s = knn_src[t * K_KNN + j];
        float c = conf[s];
        const float* Rs = R0 + s * 9;
#pragma unroll
        for (int k = 0; k < 9; ++k) nR[k] += c * Rs[k];
        nt0 += c * t0[s * 3 + 0];
        nt1 += c * t0[s * 3 + 1];
        nt2 += c * t0[s * 3 + 2];
        den += c;
    }
    float inv = 1.0f / den;
    float Ro[9];
#pragma unroll
    for (int k = 0; k < 9; ++k) Ro[k] = nR[k] * inv;
    float to0 = nt0 * inv, to1 = nt1 * inv, to2 = nt2 * inv;
    float px = pos0[t * 3 + 0], py = pos0[t * 3 + 1], pz = pos0[t * 3 + 2];
    out[t * 3 + 0] = Ro[0] * px + Ro[1] * py + Ro[2] * pz + to0;
    out[t * 3 + 1] = Ro[3] * px + Ro[4] * py + Ro[5] * pz + to1;
    out[t * 3 + 2] = Ro[6] * px + Ro[7] * py + Ro[8] * pz + to2;
    float* Rout = out + N_PTS * 3;
#pragma unroll
    for (int k = 0; k < 9; ++k) Rout[t * 9 + k] = Ro[k];
    float* tout = out + N_PTS * 3 + N_PTS * 9;
    tout[t * 3 + 0] = to0;
    tout[t * 3 + 1] = to1;
    tout[t * 3 + 2] = to2;
}

extern "C" void kernel_launch(void* const* d_in, const int* in_sizes, int n_in,
                              void* d_out, int out_size, void* d_ws, size_t ws_size,
                              hipStream_t stream) {
    const float* x0 = (const float*)d_in[0];
    const float* pos0 = (const float*)d_in[1];
    const float* R0 = (const float*)d_in[2];
    const float* t0 = (const float*)d_in[3];
    const int* assign01 = (const int*)d_in[4];
    const int* radius_src = (const int*)d_in[5];
    const int* knn_src = (const int*)d_in[7];

    unsigned int* packed = (unsigned int*)d_ws;       // E_RAD u32 = 6.4 MB
    float* sum1 = (float*)(packed + E_RAD);           // N f32
    float* sum2 = sum1 + N_PTS;                       // N f32
    float* conf = sum2 + N_PTS;                       // N f32
    __half* mA = (__half*)(conf + N_PTS);             // N*C half = 6.4 MB (16B-aligned)
    __half* mB = mA + N_PTS * C_DIM;                  // N*C half = 6.4 MB
    float* out = (float*)d_out;

    int layer_blocks = (N_PTS * 64 + 255) / 256;  // one wave per node

    // K2: edge weights + packed words + m1 -> packed, mA, sum1
    ew_layer1_kernel<<<layer_blocks, 256, 0, stream>>>(
        x0, pos0, R0, t0, radius_src, assign01, packed, mA, sum1);

    // K3: m2 -> mB, sum2
    layer_pk_kernel<<<layer_blocks, 256, 0, stream>>>(
        packed, mA, mB, sum2);

    // K4: m3 + fused conf
    layer3_conf_pk_kernel<<<layer_blocks, 256, 0, stream>>>(
        packed, mB, sum1, sum2, conf);

    // K5: weighted average + final transform -> d_out
    wavg_kernel<<<(N_PTS + 255) / 256, 256, 0, stream>>>(
        knn_src, conf, R0, t0, pos0, out);
}

// Round 6
// 158.127 us; speedup vs baseline: 1.0984x; 1.0984x over previous
//
#include <hip/hip_runtime.h>
#include <hip/hip_fp16.h>
#include <math.h>

#define N_PTS 50000
#define C_DIM 64
#define K_RAD 32
#define K_KNN 10
#define E_RAD (N_PTS * K_RAD)

// ROCm hip_fp16.h has no __hmax2; emit packed fp16 max directly.
__device__ inline __half2 hmax2(__half2 a, __half2 b) {
    __half2 d;
    asm("v_pk_max_f16 %0, %1, %2" : "=v"(d) : "v"(a), "v"(b));
    return d;
}

__device__ inline __half2 shfl_xor_h2(__half2 v, int mask) {
    int i = *(int*)&v;
    int r = __shfl_xor(i, mask);
    return *(__half2*)&r;
}

// ---------------- K0: pack per-node gather tables ----------------
// geo[i] = 2 x float4: {pos0.xyz, x0.x}, {x0.y, x0.z, assign_bits, 0}
// rt[i]  = 3 x float4: {R0[0..3]}, {R0[4..7]}, {R0[8], t0.xyz}
// Turns the per-edge random gathers from ~7 scalar-dword address streams
// into 2 (ew) / 4 (wavg) float4 streams.
__global__ void pack_tables_kernel(const float* __restrict__ pos0,
                                   const float* __restrict__ x0,
                                   const int* __restrict__ assign,
                                   const float* __restrict__ R0,
                                   const float* __restrict__ t0,
                                   float4* __restrict__ geo,
                                   float4* __restrict__ rt) {
    int i = blockIdx.x * blockDim.x + threadIdx.x;
    if (i >= N_PTS) return;
    float4 g0 = make_float4(pos0[3 * i], pos0[3 * i + 1], pos0[3 * i + 2], x0[3 * i]);
    float4 g1 = make_float4(x0[3 * i + 1], x0[3 * i + 2], __int_as_float(assign[i]), 0.0f);
    geo[i * 2 + 0] = g0;
    geo[i * 2 + 1] = g1;
    const float* R = R0 + 9 * i;
    rt[i * 3 + 0] = make_float4(R[0], R[1], R[2], R[3]);
    rt[i * 3 + 1] = make_float4(R[4], R[5], R[6], R[7]);
    rt[i * 3 + 2] = make_float4(R[8], t0[3 * i], t0[3 * i + 1], t0[3 * i + 2]);
}

// ---------------- K2: fused edge-weight + layer 1 (one-hot input) --------
// One wave per node. Lanes 0..31 compute the rigid weight for edge
// (node*32 + lane) using two float4 gathers from geo, pack (src<<16)|half(w)
// for later kernels, and scatter w into per-wave 64-entry LDS with atomicMax.
__global__ void ew_layer1_kernel(const float4* __restrict__ geo,
                                 const float* __restrict__ R0,
                                 const float* __restrict__ t0,
                                 const int* __restrict__ src,
                                 unsigned int* __restrict__ packed,
                                 __half* __restrict__ m1,
                                 float* __restrict__ sum1) {
    __shared__ int lm[4][C_DIM];
    int wave = (blockIdx.x * blockDim.x + threadIdx.x) >> 6;
    int lane = threadIdx.x & 63;
    int wslot = threadIdx.x >> 6;
    lm[wslot][lane] = 0;
    // grid is exact (N_PTS*64 threads): wave < N_PTS always; wave-uniform.
    int nb = __builtin_amdgcn_readfirstlane(wave);
    float w = 0.0f;
    int a = 0;
    if (lane < 32) {
        int s = src[nb * K_RAD + lane];
        float4 g0 = geo[s * 2 + 0];   // px,py,pz,xx
        float4 g1 = geo[s * 2 + 1];   // xy,xz,assign,0
        a = __float_as_int(g1.z);
        const float* R = R0 + nb * 9;       // wave-uniform -> s_load
        const float* T = t0 + nb * 3;
        float r0 = R[0] * g0.x + R[1] * g0.y + R[2] * g0.z + T[0] - g0.w;
        float r1 = R[3] * g0.x + R[4] * g0.y + R[5] * g0.z + T[1] - g1.x;
        float r2 = R[6] * g0.x + R[7] * g0.y + R[8] * g0.z + T[2] - g1.y;
        float dsq = r0 * r0 + r1 * r1 + r2 * r2;
        w = 1.0f / (1.0f + __expf(dsq - 0.01f));
        unsigned int wb = (unsigned int)__half_as_ushort(__float2half_rn(w));
        packed[nb * K_RAD + lane] = ((unsigned int)s << 16) | wb;
    }
    __syncthreads();
    if (lane < 32) atomicMax(&lm[wslot][a], __float_as_int(w));
    __syncthreads();
    float m = __int_as_float(lm[wslot][lane]);
    if (lane < 32) {
        float lo = __int_as_float(lm[wslot][2 * lane]);
        float hi = __int_as_float(lm[wslot][2 * lane + 1]);
        *(__half2*)(m1 + wave * C_DIM + 2 * lane) = __floats2half2_rn(lo, hi);
    }
    float ssum = m;
#pragma unroll
    for (int off = 32; off > 0; off >>= 1) ssum += __shfl_down(ssum, off);
    if (lane == 0) sum1[wave] = ssum;
}

// ---------------- K3: wide-gather fp16 layer ----------------
// One wave per node. lane = (eslot in [0,8), cpos in [0,8)).
// Iteration p: edge e = p*8+eslot; one bpermute of packed (src,w), one 16B
// global_load_dwordx4 covering channels [cpos*8, cpos*8+8). Only 4 iters.
__global__ void layer_pk_kernel(const unsigned int* __restrict__ packed,
                                const __half* __restrict__ xin,
                                __half* __restrict__ xout,
                                float* __restrict__ sum_out) {
    int wave = (blockIdx.x * blockDim.x + threadIdx.x) >> 6;
    int lane = threadIdx.x & 63;
    if (wave >= N_PTS) return;
    int eslot = lane >> 3;
    int cpos = lane & 7;
    unsigned int pk = packed[wave * K_RAD + (lane & 31)];
    __half2 a0 = __float2half2_rn(0.0f), a1 = a0, a2 = a0, a3 = a0;
#pragma unroll
    for (int p = 0; p < 4; ++p) {
        unsigned int pe = (unsigned int)__shfl((int)pk, p * 8 + eslot);
        float4 f = *(const float4*)(xin + (pe >> 16) * C_DIM + cpos * 8);
        __half2* h = (__half2*)&f;
        __half2 w2 = __half2half2(__ushort_as_half((unsigned short)(pe & 0xffffu)));
        a0 = hmax2(a0, __hmul2(w2, h[0]));
        a1 = hmax2(a1, __hmul2(w2, h[1]));
        a2 = hmax2(a2, __hmul2(w2, h[2]));
        a3 = hmax2(a3, __hmul2(w2, h[3]));
    }
#pragma unroll
    for (int off = 8; off < 64; off <<= 1) {
        a0 = hmax2(a0, shfl_xor_h2(a0, off));
        a1 = hmax2(a1, shfl_xor_h2(a1, off));
        a2 = hmax2(a2, shfl_xor_h2(a2, off));
        a3 = hmax2(a3, shfl_xor_h2(a3, off));
    }
    if (eslot == 0) {
        float4 o;
        __half2* oh = (__half2*)&o;
        oh[0] = a0; oh[1] = a1; oh[2] = a2; oh[3] = a3;
        ((float4*)(xout + wave * C_DIM))[cpos] = o;
    }
    float2 v0 = __half22float2(a0), v1 = __half22float2(a1);
    float2 v2 = __half22float2(a2), v3 = __half22float2(a3);
    float s = v0.x + v0.y + v1.x + v1.y + v2.x + v2.y + v3.x + v3.y;
#pragma unroll
    for (int off = 1; off < 8; off <<= 1) s += __shfl_xor(s, off);
    if (lane == 0) sum_out[wave] = s;
}

// ---------------- K4: wide-gather layer 3 + fused confidence ----------------
// m3 == m4 == m5  =>  conf = sigmoid(sum1 + sum2 + 3*sum3 - 17)
__global__ void layer3_conf_pk_kernel(const unsigned int* __restrict__ packed,
                                      const __half* __restrict__ xin,
                                      const float* __restrict__ sum1,
                                      const float* __restrict__ sum2,
                                      float* __restrict__ conf) {
    int wave = (blockIdx.x * blockDim.x + threadIdx.x) >> 6;
    int lane = threadIdx.x & 63;
    if (wave >= N_PTS) return;
    int eslot = lane >> 3;
    int cpos = lane & 7;
    unsigned int pk = packed[wave * K_RAD + (lane & 31)];
    __half2 a0 = __float2half2_rn(0.0f), a1 = a0, a2 = a0, a3 = a0;
#pragma unroll
    for (int p = 0; p < 4; ++p) {
        unsigned int pe = (unsigned int)__shfl((int)pk, p * 8 + eslot);
        float4 f = *(const float4*)(xin + (pe >> 16) * C_DIM + cpos * 8);
        __half2* h = (__half2*)&f;
        __half2 w2 = __half2half2(__ushort_as_half((unsigned short)(pe & 0xffffu)));
        a0 = hmax2(a0, __hmul2(w2, h[0]));
        a1 = hmax2(a1, __hmul2(w2, h[1]));
        a2 = hmax2(a2, __hmul2(w2, h[2]));
        a3 = hmax2(a3, __hmul2(w2, h[3]));
    }
#pragma unroll
    for (int off = 8; off < 64; off <<= 1) {
        a0 = hmax2(a0, shfl_xor_h2(a0, off));
        a1 = hmax2(a1, shfl_xor_h2(a1, off));
        a2 = hmax2(a2, shfl_xor_h2(a2, off));
        a3 = hmax2(a3, shfl_xor_h2(a3, off));
    }
    float2 v0 = __half22float2(a0), v1 = __half22float2(a1);
    float2 v2 = __half22float2(a2), v3 = __half22float2(a3);
    float s = v0.x + v0.y + v1.x + v1.y + v2.x + v2.y + v3.x + v3.y;
#pragma unroll
    for (int off = 1; off < 8; off <<= 1) s += __shfl_xor(s, off);
    if (lane == 0) {
        float tot = sum1[wave] + sum2[wave] + 3.0f * s - 17.0f;
        conf[wave] = 1.0f / (1.0f + __expf(-tot));
    }
}

// ---------------- K5: weighted average over knn + rigid transform --------
// Uses packed rt table: 4 random float4 gathers per edge instead of 13 dwords.
__global__ void wavg_kernel(const int* __restrict__ knn_src,
                            const float* __restrict__ conf,
                            const float4* __restrict__ rt,
                            const float* __restrict__ pos0,
                            float* __restrict__ out) {
    int t = blockIdx.x * blockDim.x + threadIdx.x;
    if (t >= N_PTS) return;
    float nR[9] = {0, 0, 0, 0, 0, 0, 0, 0, 0};
    float nt0 = 0.0f, nt1 = 0.0f, nt2 = 0.0f;
    float den = 1e-8f;
    for (int j = 0; j < K_KNN; ++j) {
        int s = knn_src[t * K_KNN + j];
        float c = conf[s];
        float4 q0 = rt[s * 3 + 0];   // R0..R3
        float4 q1 = rt[s * 3 + 1];   // R4..R7
        float4 q2 = rt[s * 3 + 2];   // R8, t.xyz
        nR[0] += c * q0.x; nR[1] += c * q0.y; nR[2] += c * q0.z; nR[3] += c * q0.w;
        nR[4] += c * q1.x; nR[5] += c * q1.y; nR[6] += c * q1.z; nR[7] += c * q1.w;
        nR[8] += c * q2.x;
        nt0 += c * q2.y; nt1 += c * q2.z; nt2 += c * q2.w;
        den += c;
    }
    float inv = 1.0f / den;
    float Ro[9];
#pragma unroll
    for (int k = 0; k < 9; ++k) Ro[k] = nR[k] * inv;
    float to0 = nt0 * inv, to1 = nt1 * inv, to2 = nt2 * inv;
    float px = pos0[t * 3 + 0], py = pos0[t * 3 + 1], pz = pos0[t * 3 + 2];
    out[t * 3 + 0] = Ro[0] * px + Ro[1] * py + Ro[2] * pz + to0;
    out[t * 3 + 1] = Ro[3] * px + Ro[4] * py + Ro[5] * pz + to1;
    out[t * 3 + 2] = Ro[6] * px + Ro[7] * py + Ro[8] * pz + to2;
    float* Rout = out + N_PTS * 3;
#pragma unroll
    for (int k = 0; k < 9; ++k) Rout[t * 9 + k] = Ro[k];
    float* tout = out + N_PTS * 3 + N_PTS * 9;
    tout[t * 3 + 0] = to0;
    tout[t * 3 + 1] = to1;
    tout[t * 3 + 2] = to2;
}

extern "C" void kernel_launch(void* const* d_in, const int* in_sizes, int n_in,
                              void* d_out, int out_size, void* d_ws, size_t ws_size,
                              hipStream_t stream) {
    const float* x0 = (const float*)d_in[0];
    const float* pos0 = (const float*)d_in[1];
    const float* R0 = (const float*)d_in[2];
    const float* t0 = (const float*)d_in[3];
    const int* assign01 = (const int*)d_in[4];
    const int* radius_src = (const int*)d_in[5];
    const int* knn_src = (const int*)d_in[7];

    char* ws = (char*)d_ws;
    unsigned int* packed = (unsigned int*)ws;                  // 6,400,000 B
    float* sum1 = (float*)(ws + 6400000);                      //   200,000 B
    float* sum2 = (float*)(ws + 6600000);                      //   200,000 B
    float* conf = (float*)(ws + 6800000);                      //   200,000 B
    __half* mA = (__half*)(ws + 7000000);                      // 6,400,000 B
    __half* mB = (__half*)(ws + 13400000);                     // 6,400,000 B
    float4* geo = (float4*)(ws + 19800000);                    // 1,600,000 B
    float4* rt = (float4*)(ws + 21400000);                     // 2,400,000 B
    float* out = (float*)d_out;

    int layer_blocks = (N_PTS * 64 + 255) / 256;  // one wave per node

    // K0: pack gather tables
    pack_tables_kernel<<<(N_PTS + 255) / 256, 256, 0, stream>>>(
        pos0, x0, assign01, R0, t0, geo, rt);

    // K2: edge weights + packed words + m1 -> packed, mA, sum1
    ew_layer1_kernel<<<layer_blocks, 256, 0, stream>>>(
        geo, R0, t0, radius_src, packed, mA, sum1);

    // K3: m2 -> mB, sum2
    layer_pk_kernel<<<layer_blocks, 256, 0, stream>>>(
        packed, mA, mB, sum2);

    // K4: m3 + fused conf
    layer3_conf_pk_kernel<<<layer_blocks, 256, 0, stream>>>(
        packed, mB, sum1, sum2, conf);

    // K5: weighted average + final transform -> d_out
    wavg_kernel<<<(N_PTS + 255) / 256, 256, 0, stream>>>(
        knn_src, conf, rt, pos0, out);
}

// Round 7
// 140.813 us; speedup vs baseline: 1.2335x; 1.1230x over previous
//
#include <hip/hip_runtime.h>
#include <hip/hip_fp16.h>
#include <math.h>

#define N_PTS 50000
#define C_DIM 64
#define K_RAD 32
#define K_KNN 10
#define E_RAD (N_PTS * K_RAD)

// ROCm hip_fp16.h has no __hmax2; emit packed fp16 max directly.
__device__ inline __half2 hmax2(__half2 a, __half2 b) {
    __half2 d;
    asm("v_pk_max_f16 %0, %1, %2" : "=v"(d) : "v"(a), "v"(b));
    return d;
}

__device__ inline __half2 shfl_xor_h2(__half2 v, int mask) {
    int i = *(int*)&v;
    int r = __shfl_xor(i, mask);
    return *(__half2*)&r;
}

// ---------------- K0: pack per-node gather tables ----------------
// geo[i] = 2 x float4: {pos0.xyz, x0.x}, {x0.y, x0.z, assign_bits, 0}
// rt[i]  = 3 x float4: {R0[0..3]}, {R0[4..7]}, {R0[8], t0.xyz}
__global__ void pack_tables_kernel(const float* __restrict__ pos0,
                                   const float* __restrict__ x0,
                                   const int* __restrict__ assign,
                                   const float* __restrict__ R0,
                                   const float* __restrict__ t0,
                                   float4* __restrict__ geo,
                                   float4* __restrict__ rt) {
    int i = blockIdx.x * blockDim.x + threadIdx.x;
    if (i >= N_PTS) return;
    float4 g0 = make_float4(pos0[3 * i], pos0[3 * i + 1], pos0[3 * i + 2], x0[3 * i]);
    float4 g1 = make_float4(x0[3 * i + 1], x0[3 * i + 2], __int_as_float(assign[i]), 0.0f);
    geo[i * 2 + 0] = g0;
    geo[i * 2 + 1] = g1;
    const float* R = R0 + 9 * i;
    rt[i * 3 + 0] = make_float4(R[0], R[1], R[2], R[3]);
    rt[i * 3 + 1] = make_float4(R[4], R[5], R[6], R[7]);
    rt[i * 3 + 2] = make_float4(R[8], t0[3 * i], t0[3 * i + 1], t0[3 * i + 2]);
}

// ---------------- K2: fused edge-weight + layer 1 (one-hot input) --------
__global__ void ew_layer1_kernel(const float4* __restrict__ geo,
                                 const float* __restrict__ R0,
                                 const float* __restrict__ t0,
                                 const int* __restrict__ src,
                                 unsigned int* __restrict__ packed,
                                 __half* __restrict__ m1,
                                 float* __restrict__ sum1) {
    __shared__ int lm[4][C_DIM];
    int wave = (blockIdx.x * blockDim.x + threadIdx.x) >> 6;
    int lane = threadIdx.x & 63;
    int wslot = threadIdx.x >> 6;
    lm[wslot][lane] = 0;
    // grid is exact (N_PTS*64 threads): wave < N_PTS always; wave-uniform.
    int nb = __builtin_amdgcn_readfirstlane(wave);
    float w = 0.0f;
    int a = 0;
    if (lane < 32) {
        int s = src[nb * K_RAD + lane];
        float4 g0 = geo[s * 2 + 0];   // px,py,pz,xx
        float4 g1 = geo[s * 2 + 1];   // xy,xz,assign,0
        a = __float_as_int(g1.z);
        const float* R = R0 + nb * 9;       // wave-uniform -> s_load
        const float* T = t0 + nb * 3;
        float r0 = R[0] * g0.x + R[1] * g0.y + R[2] * g0.z + T[0] - g0.w;
        float r1 = R[3] * g0.x + R[4] * g0.y + R[5] * g0.z + T[1] - g1.x;
        float r2 = R[6] * g0.x + R[7] * g0.y + R[8] * g0.z + T[2] - g1.y;
        float dsq = r0 * r0 + r1 * r1 + r2 * r2;
        w = 1.0f / (1.0f + __expf(dsq - 0.01f));
        unsigned int wb = (unsigned int)__half_as_ushort(__float2half_rn(w));
        packed[nb * K_RAD + lane] = ((unsigned int)s << 16) | wb;
    }
    __syncthreads();
    if (lane < 32) atomicMax(&lm[wslot][a], __float_as_int(w));
    __syncthreads();
    float m = __int_as_float(lm[wslot][lane]);
    if (lane < 32) {
        float lo = __int_as_float(lm[wslot][2 * lane]);
        float hi = __int_as_float(lm[wslot][2 * lane + 1]);
        *(__half2*)(m1 + wave * C_DIM + 2 * lane) = __floats2half2_rn(lo, hi);
    }
    float ssum = m;
#pragma unroll
    for (int off = 32; off > 0; off >>= 1) ssum += __shfl_down(ssum, off);
    if (lane == 0) sum1[wave] = ssum;
}

// ---------------- K3: wide-gather fp16 layer ----------------
// One wave per node. lane = (eslot in [0,8), cpos in [0,8)).
// Iteration p: edge e = p*8+eslot. The packed (src,w) word is loaded
// directly (8 distinct dwords in one 128B line, broadcast in-instruction)
// instead of bpermute; one 16B gather covers channels [cpos*8, cpos*8+8).
__global__ void layer_pk_kernel(const unsigned int* __restrict__ packed,
                                const __half* __restrict__ xin,
                                __half* __restrict__ xout,
                                float* __restrict__ sum_out) {
    int wave = (blockIdx.x * blockDim.x + threadIdx.x) >> 6;
    int lane = threadIdx.x & 63;
    if (wave >= N_PTS) return;
    int eslot = lane >> 3;
    int cpos = lane & 7;
    const unsigned int* pkrow = packed + wave * K_RAD;
    __half2 a0 = __float2half2_rn(0.0f), a1 = a0, a2 = a0, a3 = a0;
#pragma unroll
    for (int p = 0; p < 4; ++p) {
        unsigned int pe = pkrow[p * 8 + eslot];
        float4 f = *(const float4*)(xin + (pe >> 16) * C_DIM + cpos * 8);
        __half2* h = (__half2*)&f;
        __half2 w2 = __half2half2(__ushort_as_half((unsigned short)(pe & 0xffffu)));
        a0 = hmax2(a0, __hmul2(w2, h[0]));
        a1 = hmax2(a1, __hmul2(w2, h[1]));
        a2 = hmax2(a2, __hmul2(w2, h[2]));
        a3 = hmax2(a3, __hmul2(w2, h[3]));
    }
#pragma unroll
    for (int off = 8; off < 64; off <<= 1) {
        a0 = hmax2(a0, shfl_xor_h2(a0, off));
        a1 = hmax2(a1, shfl_xor_h2(a1, off));
        a2 = hmax2(a2, shfl_xor_h2(a2, off));
        a3 = hmax2(a3, shfl_xor_h2(a3, off));
    }
    if (eslot == 0) {
        float4 o;
        __half2* oh = (__half2*)&o;
        oh[0] = a0; oh[1] = a1; oh[2] = a2; oh[3] = a3;
        ((float4*)(xout + wave * C_DIM))[cpos] = o;
    }
    float2 v0 = __half22float2(a0), v1 = __half22float2(a1);
    float2 v2 = __half22float2(a2), v3 = __half22float2(a3);
    float s = v0.x + v0.y + v1.x + v1.y + v2.x + v2.y + v3.x + v3.y;
#pragma unroll
    for (int off = 1; off < 8; off <<= 1) s += __shfl_xor(s, off);
    if (lane == 0) sum_out[wave] = s;
}

// ---------------- K4: wide-gather layer 3 + fused confidence ----------------
// m3 == m4 == m5  =>  conf = sigmoid(sum1 + sum2 + 3*sum3 - 17)
__global__ void layer3_conf_pk_kernel(const unsigned int* __restrict__ packed,
                                      const __half* __restrict__ xin,
                                      const float* __restrict__ sum1,
                                      const float* __restrict__ sum2,
                                      float* __restrict__ conf) {
    int wave = (blockIdx.x * blockDim.x + threadIdx.x) >> 6;
    int lane = threadIdx.x & 63;
    if (wave >= N_PTS) return;
    int eslot = lane >> 3;
    int cpos = lane & 7;
    const unsigned int* pkrow = packed + wave * K_RAD;
    __half2 a0 = __float2half2_rn(0.0f), a1 = a0, a2 = a0, a3 = a0;
#pragma unroll
    for (int p = 0; p < 4; ++p) {
        unsigned int pe = pkrow[p * 8 + eslot];
        float4 f = *(const float4*)(xin + (pe >> 16) * C_DIM + cpos * 8);
        __half2* h = (__half2*)&f;
        __half2 w2 = __half2half2(__ushort_as_half((unsigned short)(pe & 0xffffu)));
        a0 = hmax2(a0, __hmul2(w2, h[0]));
        a1 = hmax2(a1, __hmul2(w2, h[1]));
        a2 = hmax2(a2, __hmul2(w2, h[2]));
        a3 = hmax2(a3, __hmul2(w2, h[3]));
    }
#pragma unroll
    for (int off = 8; off < 64; off <<= 1) {
        a0 = hmax2(a0, shfl_xor_h2(a0, off));
        a1 = hmax2(a1, shfl_xor_h2(a1, off));
        a2 = hmax2(a2, shfl_xor_h2(a2, off));
        a3 = hmax2(a3, shfl_xor_h2(a3, off));
    }
    float2 v0 = __half22float2(a0), v1 = __half22float2(a1);
    float2 v2 = __half22float2(a2), v3 = __half22float2(a3);
    float s = v0.x + v0.y + v1.x + v1.y + v2.x + v2.y + v3.x + v3.y;
#pragma unroll
    for (int off = 1; off < 8; off <<= 1) s += __shfl_xor(s, off);
    if (lane == 0) {
        float tot = sum1[wave] + sum2[wave] + 3.0f * s - 17.0f;
        conf[wave] = 1.0f / (1.0f + __expf(-tot));
    }
}

// ---------------- K5: weighted average over knn + rigid transform --------
__global__ void wavg_kernel(const int* __restrict__ knn_src,
                            const float* __restrict__ conf,
                            const float4* __restrict__ rt,
                            const float* __restrict__ pos0,
                            float* __restrict__ out) {
    int t = blockIdx.x * blockDim.x + threadIdx.x;
    if (t >= N_PTS) return;
    float nR[9] = {0, 0, 0, 0, 0, 0, 0, 0, 0};
    float nt0 = 0.0f, nt1 = 0.0f, nt2 = 0.0f;
    float den = 1e-8f;
    for (int j = 0; j < K_KNN; ++j) {
        int s = knn_src[t * K_KNN + j];
        float c = conf[s];
        float4 q0 = rt[s * 3 + 0];   // R0..R3
        float4 q1 = rt[s * 3 + 1];   // R4..R7
        float4 q2 = rt[s * 3 + 2];   // R8, t.xyz
        nR[0] += c * q0.x; nR[1] += c * q0.y; nR[2] += c * q0.z; nR[3] += c * q0.w;
        nR[4] += c * q1.x; nR[5] += c * q1.y; nR[6] += c * q1.z; nR[7] += c * q1.w;
        nR[8] += c * q2.x;
        nt0 += c * q2.y; nt1 += c * q2.z; nt2 += c * q2.w;
        den += c;
    }
    float inv = 1.0f / den;
    float Ro[9];
#pragma unroll
    for (int k = 0; k < 9; ++k) Ro[k] = nR[k] * inv;
    float to0 = nt0 * inv, to1 = nt1 * inv, to2 = nt2 * inv;
    float px = pos0[t * 3 + 0], py = pos0[t * 3 + 1], pz = pos0[t * 3 + 2];
    out[t * 3 + 0] = Ro[0] * px + Ro[1] * py + Ro[2] * pz + to0;
    out[t * 3 + 1] = Ro[3] * px + Ro[4] * py + Ro[5] * pz + to1;
    out[t * 3 + 2] = Ro[6] * px + Ro[7] * py + Ro[8] * pz + to2;
    float* Rout = out + N_PTS * 3;
#pragma unroll
    for (int k = 0; k < 9; ++k) Rout[t * 9 + k] = Ro[k];
    float* tout = out + N_PTS * 3 + N_PTS * 9;
    tout[t * 3 + 0] = to0;
    tout[t * 3 + 1] = to1;
    tout[t * 3 + 2] = to2;
}

extern "C" void kernel_launch(void* const* d_in, const int* in_sizes, int n_in,
                              void* d_out, int out_size, void* d_ws, size_t ws_size,
                              hipStream_t stream) {
    const float* x0 = (const float*)d_in[0];
    const float* pos0 = (const float*)d_in[1];
    const float* R0 = (const float*)d_in[2];
    const float* t0 = (const float*)d_in[3];
    const int* assign01 = (const int*)d_in[4];
    const int* radius_src = (const int*)d_in[5];
    const int* knn_src = (const int*)d_in[7];

    // All large tables 128-B aligned so every 128-B feature row is exactly
    // one TCC line (offsets are multiples of 128).
    char* ws = (char*)d_ws;
    unsigned int* packed = (unsigned int*)ws;                  // @0         6,400,000 B
    __half* mA = (__half*)(ws + 6400000);                      // @6,400,000 6,400,000 B
    __half* mB = (__half*)(ws + 12800000);                     // @12,800,000 6,400,000 B
    float4* geo = (float4*)(ws + 19200000);                    // @19,200,000 1,600,000 B
    float4* rt = (float4*)(ws + 20800000);                     // @20,800,000 2,400,000 B
    float* sum1 = (float*)(ws + 23200000);                     // 200,000 B
    float* sum2 = (float*)(ws + 23400000);                     // 200,000 B
    float* conf = (float*)(ws + 23600000);                     // 200,000 B
    float* out = (float*)d_out;

    int layer_blocks = (N_PTS * 64 + 255) / 256;  // one wave per node

    // K0: pack gather tables
    pack_tables_kernel<<<(N_PTS + 255) / 256, 256, 0, stream>>>(
        pos0, x0, assign01, R0, t0, geo, rt);

    // K2: edge weights + packed words + m1 -> packed, mA, sum1
    ew_layer1_kernel<<<layer_blocks, 256, 0, stream>>>(
        geo, R0, t0, radius_src, packed, mA, sum1);

    // K3: m2 -> mB, sum2
    layer_pk_kernel<<<layer_blocks, 256, 0, stream>>>(
        packed, mA, mB, sum2);

    // K4: m3 + fused conf
    layer3_conf_pk_kernel<<<layer_blocks, 256, 0, stream>>>(
        packed, mB, sum1, sum2, conf);

    // K5: weighted average + final transform -> d_out
    wavg_kernel<<<(N_PTS + 255) / 256, 256, 0, stream>>>(
        knn_src, conf, rt, pos0, out);
}